// Round 4
// baseline (6070.634 us; speedup 1.0000x reference)
//
#include <hip/hip_runtime.h>
#include <stdint.h>

// Problem constants: B=32, T=512, I=1024, H=1024, 4H=4096, M=B*T=16384.
#define BB 32
#define TT 512
#define KK 1024
#define GG 4096
#define MM 16384

typedef __attribute__((ext_vector_type(8))) short short8;
typedef __attribute__((ext_vector_type(4))) short short4v;
typedef __attribute__((ext_vector_type(4))) float f32x4;
typedef unsigned long long u64;

__device__ inline short f2bf(float f) {
  union { float f; unsigned u; } v; v.f = f;
  unsigned r = (v.u + 0x7FFFu + ((v.u >> 16) & 1u)) >> 16;  // RNE
  return (short)(unsigned short)r;
}
__device__ inline float bf2f(short s) {
  union { unsigned u; float f; } v; v.u = ((unsigned)(unsigned short)s) << 16;
  return v.f;
}
__device__ inline float sigmoid_f(float x) { return 1.0f / (1.0f + __expf(-x)); }
__device__ inline float tanh_f(float x)    { return 1.0f - 2.0f / (__expf(2.0f * x) + 1.0f); }

// ---------------- prep kernels ----------------

__global__ void zero_ws(unsigned* __restrict__ p, int n) {
  int i = blockIdx.x * 256 + threadIdx.x;
  if (i < n) p[i] = 0u;
}

// float -> bf16, 4 elements/thread
__global__ void cvt_bf16(const float* __restrict__ in, short* __restrict__ out, int n4) {
  int i = blockIdx.x * 256 + threadIdx.x;
  if (i >= n4) return;
  f32x4 v = *(const f32x4*)(in + (size_t)i * 4);
  short4v o;
  o.x = f2bf(v.x); o.y = f2bf(v.y); o.z = f2bf(v.z); o.w = f2bf(v.w);
  *(short4v*)(out + (size_t)i * 4) = o;
}

// Pack W_hh into per-wave MFMA-B-fragment order for the scan.
// Col-group wgp (0..63) owns H-cols wgp*16..+15; wave wv4 (0..3) owns the
// 4 H-cols wgp*16 + wv4*4 + c, for all 4 gates, interleaved in the n-tile:
//   n = g*4 + c  ->  row(W_hh) = g*1024 + wgp*16 + wv4*4 + c
//   k(W_hh)      = s*32 + (lane>>4)*8 + j            (s = 0..31, full K)
// wpack[((wgp*4 + wv4)*32 + s)*512 + lane*8 + j]
__global__ void pack_whh(const float* __restrict__ Whh, short* __restrict__ wpack) {
  int idx = blockIdx.x * 256 + threadIdx.x;          // < 64*4*32*64 = 524288
  if (idx >= 524288) return;
  int lane = idx & 63;
  int s    = (idx >> 6) & 31;
  int wv4  = (idx >> 11) & 3;
  int wgp  = idx >> 13;
  int n = lane & 15, g = n >> 2, c = n & 3;
  int row  = g * 1024 + wgp * 16 + wv4 * 4 + c;
  int k    = s * 32 + (lane >> 4) * 8;
  const float* src = Whh + (size_t)row * KK + k;
  short8 v;
#pragma unroll
  for (int j = 0; j < 8; ++j) v[j] = f2bf(src[j]);
  *(short8*)(wpack + ((size_t)((wgp * 4 + wv4) * 32 + s)) * 512 + lane * 8) = v;
}

// ---------------- phase 1: xW = x @ W_ih^T + b ----------------
// A = x bf16 [16384][1024]; B = W_ih bf16 [4096][1024] (row-major = B^T form).
// 128x128 tile, BK=32, 256 threads (4 waves in 2x2), 4x4 MFMA tiles per wave.
template <bool XWF32>
__global__ __launch_bounds__(256) void gemm_xw(const short* __restrict__ A,
                                               const short* __restrict__ Bw,
                                               const float* __restrict__ bias,
                                               void* __restrict__ Cv) {
  __shared__ short As[128 * 32];
  __shared__ short Bs[128 * 32];
  const int tid = threadIdx.x;
  const int m0 = blockIdx.y * 128;
  const int n0 = blockIdx.x * 128;
  const int lane = tid & 63, wv = tid >> 6;
  const int wm = (wv >> 1) * 64, wn = (wv & 1) * 64;
  const int fr = lane & 15;               // fragment row/col
  const int fq = (lane >> 4) * 8;         // k-offset (elements)
  const int quad = lane >> 4;
  f32x4 acc[4][4];
#pragma unroll
  for (int i = 0; i < 4; ++i)
#pragma unroll
    for (int j = 0; j < 4; ++j) acc[i][j] = (f32x4){0.f, 0.f, 0.f, 0.f};

  const int sr = tid >> 2;                // staging row 0..63
  const int sc = (tid & 3) * 8;           // staging elem offset
  const short* Ag = A + (size_t)(m0 + sr) * KK + sc;
  const short* Bg = Bw + (size_t)(n0 + sr) * KK + sc;

  for (int kb = 0; kb < KK; kb += 32) {
    short8 a0 = *(const short8*)(Ag + kb);
    short8 a1 = *(const short8*)(Ag + (size_t)64 * KK + kb);
    short8 b0 = *(const short8*)(Bg + kb);
    short8 b1 = *(const short8*)(Bg + (size_t)64 * KK + kb);
    __syncthreads();
    *(short8*)&As[sr * 32 + sc] = a0;
    *(short8*)&As[(64 + sr) * 32 + sc] = a1;
    *(short8*)&Bs[sr * 32 + sc] = b0;
    *(short8*)&Bs[(64 + sr) * 32 + sc] = b1;
    __syncthreads();
    short8 af[4], bf[4];
#pragma unroll
    for (int i = 0; i < 4; ++i) {
      af[i] = *(const short8*)&As[(wm + i * 16 + fr) * 32 + fq];
      bf[i] = *(const short8*)&Bs[(wn + i * 16 + fr) * 32 + fq];
    }
#pragma unroll
    for (int i = 0; i < 4; ++i)
#pragma unroll
      for (int j = 0; j < 4; ++j)
        acc[i][j] = __builtin_amdgcn_mfma_f32_16x16x32_bf16(af[i], bf[j], acc[i][j], 0, 0, 0);
  }
  // epilogue: C/D layout col=lane&15, row=(lane>>4)*4+reg
#pragma unroll
  for (int i = 0; i < 4; ++i) {
    int mrow = m0 + wm + i * 16 + quad * 4;
#pragma unroll
    for (int j = 0; j < 4; ++j) {
      int ncol = n0 + wn + j * 16 + fr;
      float bv = bias[ncol];
#pragma unroll
      for (int r = 0; r < 4; ++r) {
        float v = acc[i][j][r] + bv;
        size_t idx = (size_t)(mrow + r) * GG + ncol;
        if (XWF32) ((float*)Cv)[idx] = v;
        else       ((short*)Cv)[idx] = f2bf(v);
      }
    }
  }
}

// ---------------- persistent LSTM scan (tagged-chunk exchange) ----------------
// 128 WGs x 256 thr: blockIdx = (wgp = col-group 0..63) * 2 + (half 0..1).
// half owns batch rows half*16..+15; the two halves are independent 64-WG
// exchange groups. Each wave (wv4 0..3) owns 4 H-cols x 4 gates = one 16x16
// n-tile (n = g*4+c), full K=1024 (32 MFMAs), W_hh B-frags in 128 VGPRs.
// h exchange: u64 chunks [tag32 | h_even bf16 | h_odd bf16<<16], relaxed
// agent-scope (sc1) atomics, parity double-buffered. NO flags, NO fences,
// NO vmcnt drains on the critical path: consumers retry chunks whose tag != t.
// Safety: a producer reaches step t+2 only after consuming every tag-(t+1)
// chunk, which requires all WGs to have finished step t -> buf[t&1] is never
// overwritten while a reader still wants tag t.
template <bool XWF32>
__global__ __launch_bounds__(256) void lstm_scan(const void* __restrict__ xWv,
                                                 const short* __restrict__ wpack,
                                                 u64* __restrict__ hbuf,
                                                 float* __restrict__ out) {
  const int wgp  = blockIdx.x >> 1;
  const int half = blockIdx.x & 1;
  const int tid  = threadIdx.x;
  const int lane = tid & 63;
  const int wv4  = tid >> 6;              // 0..3
  const int quad = lane >> 4;
  const int abrow = lane & 15;            // A-frag m index (local batch row)

  // preload W_hh B-fragments: 32 x short8 = 128 VGPRs per lane
  short8 wreg[32];
  {
    const short* wp = wpack + ((size_t)((wgp * 4 + wv4) * 32)) * 512 + lane * 8;
#pragma unroll
    for (int s = 0; s < 32; ++s) wreg[s] = *(const short8*)(wp + (size_t)s * 512);
  }

  __shared__ unsigned hstage[16 * 516];       // 16 h rows x 512 u32 (+4 pad), 33 KB
  __shared__ float partials[4 * 16 * 16];     // per-wave [n][b] z-tile, 4 KB
  const short* hs = (const short*)hstage;

  const int gb = lane >> 2, gc = lane & 3;    // gate-thread: (local b, c)
  const int colg = wgp * 16 + wv4 * 4 + gc;   // global H-col
  const int browg = half * 16 + gb;           // global batch row
  float c_reg = 0.f;

  const float* xwf = (const float*)xWv;
  const short* xwh = (const short*)xWv;

  // prefetch xW for t=0
  float xwv_[4];
#pragma unroll
  for (int g = 0; g < 4; ++g) {
    size_t xi = ((size_t)browg * TT) * GG + (size_t)g * 1024 + colg;
    xwv_[g] = XWF32 ? xwf[xi] : bf2f(xwh[xi]);
  }

#pragma unroll 1
  for (int t = 0; t < TT; ++t) {
    // ---- stage h(t): tagged chunks, retry until tag == t ----
    const u64* src = hbuf + (size_t)(t & 1) * 16384 + (size_t)half * 8192;
    u64 hv[32];
#pragma unroll
    for (int i = 0; i < 32; ++i)
      hv[i] = __hip_atomic_load(&src[i * 256 + tid], __ATOMIC_RELAXED,
                                __HIP_MEMORY_SCOPE_AGENT);
    const unsigned tg = (unsigned)t;
#pragma unroll
    for (int i = 0; i < 32; ++i) {
      u64 v = hv[i];
      while ((unsigned)(v >> 32) != tg) {
        __builtin_amdgcn_s_sleep(1);
        v = __hip_atomic_load(&src[i * 256 + tid], __ATOMIC_RELAXED,
                              __HIP_MEMORY_SCOPE_AGENT);
      }
      int idx = i * 256 + tid;
      hstage[(idx >> 9) * 516 + (idx & 511)] = (unsigned)v;
    }
    // raw barrier: order our LDS writes, WITHOUT a vmcnt drain
    asm volatile("s_waitcnt lgkmcnt(0)" ::: "memory");
    __builtin_amdgcn_s_barrier();
    asm volatile("" ::: "memory");

    // prefetch xW(t+1); latency overlaps MFMA phase
    float xwn[4];
    if (t + 1 < TT) {
#pragma unroll
      for (int g = 0; g < 4; ++g) {
        size_t xi = ((size_t)(browg * TT + t + 1)) * GG + (size_t)g * 1024 + colg;
        xwn[g] = XWF32 ? xwf[xi] : bf2f(xwh[xi]);
      }
    }

    // ---- MFMA: full K, A-frags from LDS, B-frags from registers ----
    f32x4 acc = (f32x4){0.f, 0.f, 0.f, 0.f};
#pragma unroll
    for (int s = 0; s < 32; ++s) {
      short8 a = *(const short8*)&hs[abrow * 1032 + s * 32 + quad * 8];
      acc = __builtin_amdgcn_mfma_f32_16x16x32_bf16(a, wreg[s], acc, 0, 0, 0);
    }

    // ---- intra-wave redistribute via own partials area (no barrier) ----
    // C/D: col = lane&15 = n = g*4+c, row = quad*4+reg = local b.
    // write [n][b], read 4 gates for (b=lane>>2, c=lane&3).
    *(f32x4*)&partials[wv4 * 256 + (lane & 15) * 16 + quad * 4] = acc;
    float z[4];
#pragma unroll
    for (int g = 0; g < 4; ++g)
      z[g] = partials[wv4 * 256 + (g * 4 + gc) * 16 + gb] + xwv_[g];

    float i_ = sigmoid_f(z[0]);
    float f_ = sigmoid_f(z[1]);
    float g_ = tanh_f(z[2]);
    float o_ = sigmoid_f(z[3]);
    c_reg = f_ * c_reg + i_ * g_;
    float h_ = o_ * tanh_f(c_reg);
    out[((size_t)browg * TT + t) * 1024 + colg] = h_;  // plain store, never drained

    // ---- h(t+1): pack col pair + tag, one atomic sc1 store, no wait ----
    unsigned hb16 = (unsigned)(unsigned short)f2bf(h_);
    unsigned oth = __shfl_xor(hb16, 1, 64);
    if (!(gc & 1)) {
      u64 chunk = ((u64)(unsigned)(t + 1) << 32) | (u64)(hb16 | (oth << 16));
      u64* dst = hbuf + (size_t)((t + 1) & 1) * 16384 +
                 (size_t)(half * 16 + gb) * 512 + (size_t)(colg >> 1);
      __hip_atomic_store(dst, chunk, __ATOMIC_RELAXED, __HIP_MEMORY_SCOPE_AGENT);
    }

#pragma unroll
    for (int g = 0; g < 4; ++g) xwv_[g] = xwn[g];

    // raw barrier: hstage reads of this step done (consumed by MFMA) before
    // any wave's next-step stage writes. No vmcnt drain.
    asm volatile("" ::: "memory");
    __builtin_amdgcn_s_barrier();
    asm volatile("" ::: "memory");
  }
}

// ---------------- launch ----------------

extern "C" void kernel_launch(void* const* d_in, const int* in_sizes, int n_in,
                              void* d_out, int out_size, void* d_ws, size_t ws_size,
                              hipStream_t stream) {
  const float* x    = (const float*)d_in[0];   // [32,512,1024]
  const float* Wih  = (const float*)d_in[1];   // [4096,1024]
  const float* Whh  = (const float*)d_in[2];   // [4096,1024]
  const float* bias = (const float*)d_in[3];   // [4096]
  float* out = (float*)d_out;

  char* ws = (char*)d_ws;
  // ws layout (bytes)
  const size_t o_xbf   = 0;                         // 33,554,432
  const size_t o_wih   = 33554432;                  //  8,388,608
  const size_t o_wpack = 41943040;                  //  8,388,608
  const size_t o_hbuf  = 50331648;                  //    262,144 (2 x 16384 u64)
  const size_t o_xw    = 50593792;                  // 256 MB (f32) or 128 MB (bf16)
  const bool xwf32 = ws_size >= (o_xw + (size_t)MM * GG * 4);

  short* xbf   = (short*)(ws + o_xbf);
  short* wihbf = (short*)(ws + o_wih);
  short* wpack = (short*)(ws + o_wpack);
  u64*   hbuf  = (u64*)(ws + o_hbuf);
  void*  xw    = (void*)(ws + o_xw);

  // zero h0 double-buffer (tags = 0 = step 0; ws is poisoned 0xAA each call)
  zero_ws<<<256, 256, 0, stream>>>((unsigned*)(ws + o_hbuf), 65536);
  // x -> bf16 (16,777,216 elems)
  cvt_bf16<<<16384, 256, 0, stream>>>(x, xbf, 4194304);
  // W_ih -> bf16 (4,194,304 elems)
  cvt_bf16<<<4096, 256, 0, stream>>>(Wih, wihbf, 1048576);
  // W_hh -> packed MFMA-B fragments
  pack_whh<<<2048, 256, 0, stream>>>(Whh, wpack);

  dim3 g1(GG / 128, MM / 128);  // (32, 128)
  if (xwf32) gemm_xw<true ><<<g1, 256, 0, stream>>>(xbf, wihbf, bias, xw);
  else       gemm_xw<false><<<g1, 256, 0, stream>>>(xbf, wihbf, bias, xw);

  if (xwf32) lstm_scan<true ><<<128, 256, 0, stream>>>(xw, wpack, hbuf, out);
  else       lstm_scan<false><<<128, 256, 0, stream>>>(xw, wpack, hbuf, out);
}

// Round 5
// 3887.783 us; speedup vs baseline: 1.5615x; 1.5615x over previous
//
#include <hip/hip_runtime.h>
#include <stdint.h>

// Problem constants: B=32, T=512, I=1024, H=1024, 4H=4096, M=B*T=16384.
#define BB 32
#define TT 512
#define KK 1024
#define GG 4096
#define MM 16384

typedef __attribute__((ext_vector_type(8))) short short8;
typedef __attribute__((ext_vector_type(4))) short short4v;
typedef __attribute__((ext_vector_type(4))) float f32x4;
typedef unsigned long long u64;

__device__ inline short f2bf(float f) {
  union { float f; unsigned u; } v; v.f = f;
  unsigned r = (v.u + 0x7FFFu + ((v.u >> 16) & 1u)) >> 16;  // RNE
  return (short)(unsigned short)r;
}
__device__ inline float bf2f(short s) {
  union { unsigned u; float f; } v; v.u = ((unsigned)(unsigned short)s) << 16;
  return v.f;
}
__device__ inline float sigmoid_f(float x) { return 1.0f / (1.0f + __expf(-x)); }
__device__ inline float tanh_f(float x)    { return 1.0f - 2.0f / (__expf(2.0f * x) + 1.0f); }

// ---------------- prep kernels ----------------

__global__ void zero_ws(unsigned* __restrict__ p, int n) {
  int i = blockIdx.x * 256 + threadIdx.x;
  if (i < n) p[i] = 0u;
}

// float -> bf16, 4 elements/thread
__global__ void cvt_bf16(const float* __restrict__ in, short* __restrict__ out, int n4) {
  int i = blockIdx.x * 256 + threadIdx.x;
  if (i >= n4) return;
  f32x4 v = *(const f32x4*)(in + (size_t)i * 4);
  short4v o;
  o.x = f2bf(v.x); o.y = f2bf(v.y); o.z = f2bf(v.z); o.w = f2bf(v.w);
  *(short4v*)(out + (size_t)i * 4) = o;
}

// Pack W_hh into per-wave MFMA-B-fragment order for the scan.
// Col-group wgp (0..63) owns H-cols wgp*16..+15; wave wv4 (0..3) owns the
// 4 H-cols wgp*16 + wv4*4 + c, for all 4 gates, interleaved in the n-tile:
//   n = g*4 + c  ->  row(W_hh) = g*1024 + wgp*16 + wv4*4 + c
//   k(W_hh)      = s*32 + (lane>>4)*8 + j            (s = 0..31, full K)
// wpack[((wgp*4 + wv4)*32 + s)*512 + lane*8 + j]
__global__ void pack_whh(const float* __restrict__ Whh, short* __restrict__ wpack) {
  int idx = blockIdx.x * 256 + threadIdx.x;          // < 64*4*32*64 = 524288
  if (idx >= 524288) return;
  int lane = idx & 63;
  int s    = (idx >> 6) & 31;
  int wv4  = (idx >> 11) & 3;
  int wgp  = idx >> 13;
  int n = lane & 15, g = n >> 2, c = n & 3;
  int row  = g * 1024 + wgp * 16 + wv4 * 4 + c;
  int k    = s * 32 + (lane >> 4) * 8;
  const float* src = Whh + (size_t)row * KK + k;
  short8 v;
#pragma unroll
  for (int j = 0; j < 8; ++j) v[j] = f2bf(src[j]);
  *(short8*)(wpack + ((size_t)((wgp * 4 + wv4) * 32 + s)) * 512 + lane * 8) = v;
}

// ---------------- phase 1: xW = x @ W_ih^T + b ----------------
// A = x bf16 [16384][1024]; B = W_ih bf16 [4096][1024] (row-major = B^T form).
// 128x128 tile, BK=32, 256 threads (4 waves in 2x2), 4x4 MFMA tiles per wave.
template <bool XWF32>
__global__ __launch_bounds__(256) void gemm_xw(const short* __restrict__ A,
                                               const short* __restrict__ Bw,
                                               const float* __restrict__ bias,
                                               void* __restrict__ Cv) {
  __shared__ short As[128 * 32];
  __shared__ short Bs[128 * 32];
  const int tid = threadIdx.x;
  const int m0 = blockIdx.y * 128;
  const int n0 = blockIdx.x * 128;
  const int lane = tid & 63, wv = tid >> 6;
  const int wm = (wv >> 1) * 64, wn = (wv & 1) * 64;
  const int fr = lane & 15;               // fragment row/col
  const int fq = (lane >> 4) * 8;         // k-offset (elements)
  const int quad = lane >> 4;
  f32x4 acc[4][4];
#pragma unroll
  for (int i = 0; i < 4; ++i)
#pragma unroll
    for (int j = 0; j < 4; ++j) acc[i][j] = (f32x4){0.f, 0.f, 0.f, 0.f};

  const int sr = tid >> 2;                // staging row 0..63
  const int sc = (tid & 3) * 8;           // staging elem offset
  const short* Ag = A + (size_t)(m0 + sr) * KK + sc;
  const short* Bg = Bw + (size_t)(n0 + sr) * KK + sc;

  for (int kb = 0; kb < KK; kb += 32) {
    short8 a0 = *(const short8*)(Ag + kb);
    short8 a1 = *(const short8*)(Ag + (size_t)64 * KK + kb);
    short8 b0 = *(const short8*)(Bg + kb);
    short8 b1 = *(const short8*)(Bg + (size_t)64 * KK + kb);
    __syncthreads();
    *(short8*)&As[sr * 32 + sc] = a0;
    *(short8*)&As[(64 + sr) * 32 + sc] = a1;
    *(short8*)&Bs[sr * 32 + sc] = b0;
    *(short8*)&Bs[(64 + sr) * 32 + sc] = b1;
    __syncthreads();
    short8 af[4], bf[4];
#pragma unroll
    for (int i = 0; i < 4; ++i) {
      af[i] = *(const short8*)&As[(wm + i * 16 + fr) * 32 + fq];
      bf[i] = *(const short8*)&Bs[(wn + i * 16 + fr) * 32 + fq];
    }
#pragma unroll
    for (int i = 0; i < 4; ++i)
#pragma unroll
      for (int j = 0; j < 4; ++j)
        acc[i][j] = __builtin_amdgcn_mfma_f32_16x16x32_bf16(af[i], bf[j], acc[i][j], 0, 0, 0);
  }
  // epilogue: C/D layout col=lane&15, row=(lane>>4)*4+reg
#pragma unroll
  for (int i = 0; i < 4; ++i) {
    int mrow = m0 + wm + i * 16 + quad * 4;
#pragma unroll
    for (int j = 0; j < 4; ++j) {
      int ncol = n0 + wn + j * 16 + fr;
      float bv = bias[ncol];
#pragma unroll
      for (int r = 0; r < 4; ++r) {
        float v = acc[i][j][r] + bv;
        size_t idx = (size_t)(mrow + r) * GG + ncol;
        if (XWF32) ((float*)Cv)[idx] = v;
        else       ((short*)Cv)[idx] = f2bf(v);
      }
    }
  }
}

// ---------------- persistent LSTM scan (tagged-chunk exchange) ----------------
// 128 WGs x 256 thr: blockIdx = (wgp = col-group 0..63) * 2 + (half 0..1).
// half owns batch rows half*16..+15; the two halves are independent 64-WG
// exchange groups. Each wave (wv4 0..3) owns 4 H-cols x 4 gates = one 16x16
// n-tile (n = g*4+c), full K=1024 (32 MFMAs), W_hh B-frags in 128 VGPRs.
// h exchange: u64 chunks [tag32 | h_even bf16 | h_odd bf16<<16], relaxed
// agent-scope (sc1) atomics, parity double-buffered. NO flags, NO fences,
// NO vmcnt drains on the critical path: consumers retry chunks whose tag != t,
// in BATCHED ROUNDS (issue all stale loads together -> 1 RTT/round, ~1-2
// rounds steady-state), with the next step's initial loads issued BEFORE the
// loop-end barrier so their RTT overlaps the barrier wait.
// Safety: a producer reaches step t+2 only after validating every tag-(t+1)
// chunk, which requires all its half's WGs finished step t -> buf[t&1] is
// never overwritten while a reader still wants tag t. Early-issued loads
// can only read stale data, which the tag check rejects.
// __launch_bounds__(256,1): ~230 VGPRs live (hv[32]=64 + wreg[32]=128) must
// NOT spill (r4's 160-cap spilled to scratch -> 2.7x regression).
template <bool XWF32>
__global__ __launch_bounds__(256, 1) void lstm_scan(const void* __restrict__ xWv,
                                                    const short* __restrict__ wpack,
                                                    u64* __restrict__ hbuf,
                                                    float* __restrict__ out) {
  const int wgp  = blockIdx.x >> 1;
  const int half = blockIdx.x & 1;
  const int tid  = threadIdx.x;
  const int lane = tid & 63;
  const int wv4  = tid >> 6;              // 0..3
  const int quad = lane >> 4;
  const int abrow = lane & 15;            // A-frag m index (local batch row)

  // preload W_hh B-fragments: 32 x short8 = 128 VGPRs per lane
  short8 wreg[32];
  {
    const short* wp = wpack + ((size_t)((wgp * 4 + wv4) * 32)) * 512 + lane * 8;
#pragma unroll
    for (int s = 0; s < 32; ++s) wreg[s] = *(const short8*)(wp + (size_t)s * 512);
  }

  __shared__ unsigned hstage[16 * 516];       // 16 h rows x 512 u32 (+4 pad), 33 KB
  __shared__ float partials[4 * 16 * 16];     // per-wave [n][b] z-tile, 4 KB
  const short* hs = (const short*)hstage;

  const int gb = lane >> 2, gc = lane & 3;    // gate-thread: (local b, c)
  const int colg = wgp * 16 + wv4 * 4 + gc;   // global H-col
  const int browg = half * 16 + gb;           // global batch row
  float c_reg = 0.f;

  const float* xwf = (const float*)xWv;
  const short* xwh = (const short*)xWv;

  // prefetch xW for t=0
  float xwv_[4];
#pragma unroll
  for (int g = 0; g < 4; ++g) {
    size_t xi = ((size_t)browg * TT) * GG + (size_t)g * 1024 + colg;
    xwv_[g] = XWF32 ? xwf[xi] : bf2f(xwh[xi]);
  }

  const u64* srcA = hbuf + (size_t)half * 8192;           // parity 0
  const u64* srcB = hbuf + 16384 + (size_t)half * 8192;   // parity 1

  // issue initial loads for t=0 (parity 0)
  u64 hv[32];
#pragma unroll
  for (int i = 0; i < 32; ++i)
    hv[i] = __hip_atomic_load(&srcA[i * 256 + tid], __ATOMIC_RELAXED,
                              __HIP_MEMORY_SCOPE_AGENT);

#pragma unroll 1
  for (int t = 0; t < TT; ++t) {
    const u64* src = (t & 1) ? srcB : srcA;
    const unsigned tg = (unsigned)t;

    // ---- validate staged chunks; batched retry rounds (1 RTT each) ----
    unsigned bad = 0;
#pragma unroll
    for (int i = 0; i < 32; ++i)
      if ((unsigned)(hv[i] >> 32) != tg) bad |= (1u << i);
#pragma unroll 1
    while (bad) {
#pragma unroll
      for (int i = 0; i < 32; ++i)
        if (bad & (1u << i))
          hv[i] = __hip_atomic_load(&src[i * 256 + tid], __ATOMIC_RELAXED,
                                    __HIP_MEMORY_SCOPE_AGENT);
#pragma unroll
      for (int i = 0; i < 32; ++i)
        if ((unsigned)(hv[i] >> 32) == tg) bad &= ~(1u << i);
    }
    // ---- write payloads to LDS ----
#pragma unroll
    for (int i = 0; i < 32; ++i) {
      int idx = i * 256 + tid;
      hstage[(idx >> 9) * 516 + (idx & 511)] = (unsigned)hv[i];
    }
    // raw barrier: order our LDS writes, WITHOUT a vmcnt drain
    asm volatile("s_waitcnt lgkmcnt(0)" ::: "memory");
    __builtin_amdgcn_s_barrier();
    asm volatile("" ::: "memory");

    // prefetch xW(t+1); latency overlaps MFMA phase
    float xwn[4];
    if (t + 1 < TT) {
#pragma unroll
      for (int g = 0; g < 4; ++g) {
        size_t xi = ((size_t)(browg * TT + t + 1)) * GG + (size_t)g * 1024 + colg;
        xwn[g] = XWF32 ? xwf[xi] : bf2f(xwh[xi]);
      }
    }

    // ---- MFMA: full K, A-frags from LDS, B-frags from registers ----
    f32x4 acc = (f32x4){0.f, 0.f, 0.f, 0.f};
#pragma unroll
    for (int s = 0; s < 32; ++s) {
      short8 a = *(const short8*)&hs[abrow * 1032 + s * 32 + quad * 8];
      acc = __builtin_amdgcn_mfma_f32_16x16x32_bf16(a, wreg[s], acc, 0, 0, 0);
    }

    // ---- intra-wave redistribute via own partials area (no barrier) ----
    // C/D: col = lane&15 = n = g*4+c, row = quad*4+reg = local b.
    *(f32x4*)&partials[wv4 * 256 + (lane & 15) * 16 + quad * 4] = acc;
    float z[4];
#pragma unroll
    for (int g = 0; g < 4; ++g)
      z[g] = partials[wv4 * 256 + (g * 4 + gc) * 16 + gb] + xwv_[g];

    float i_ = sigmoid_f(z[0]);
    float f_ = sigmoid_f(z[1]);
    float g_ = tanh_f(z[2]);
    float o_ = sigmoid_f(z[3]);
    c_reg = f_ * c_reg + i_ * g_;
    float h_ = o_ * tanh_f(c_reg);
    out[((size_t)browg * TT + t) * 1024 + colg] = h_;  // plain store, never drained

    // ---- h(t+1): pack col pair + tag, one atomic sc1 store, no wait ----
    unsigned hb16 = (unsigned)(unsigned short)f2bf(h_);
    unsigned oth = __shfl_xor(hb16, 1, 64);
    if (!(gc & 1)) {
      u64 chunk = ((u64)(unsigned)(t + 1) << 32) | (u64)(hb16 | (oth << 16));
      u64* dst = hbuf + (size_t)((t + 1) & 1) * 16384 +
                 (size_t)(half * 16 + gb) * 512 + (size_t)(colg >> 1);
      __hip_atomic_store(dst, chunk, __ATOMIC_RELAXED, __HIP_MEMORY_SCOPE_AGENT);
    }

#pragma unroll
    for (int g = 0; g < 4; ++g) xwv_[g] = xwn[g];

    // ---- issue next step's initial chunk loads BEFORE the barrier ----
    // (stale reads are rejected by the tag check next iteration)
    if (t + 1 < TT) {
      const u64* nsrc = ((t + 1) & 1) ? srcB : srcA;
#pragma unroll
      for (int i = 0; i < 32; ++i)
        hv[i] = __hip_atomic_load(&nsrc[i * 256 + tid], __ATOMIC_RELAXED,
                                  __HIP_MEMORY_SCOPE_AGENT);
    }

    // raw barrier: this step's hstage reads (consumed by MFMA) complete
    // before any wave's next-step stage writes. No vmcnt drain.
    asm volatile("" ::: "memory");
    __builtin_amdgcn_s_barrier();
    asm volatile("" ::: "memory");
  }
}

// ---------------- launch ----------------

extern "C" void kernel_launch(void* const* d_in, const int* in_sizes, int n_in,
                              void* d_out, int out_size, void* d_ws, size_t ws_size,
                              hipStream_t stream) {
  const float* x    = (const float*)d_in[0];   // [32,512,1024]
  const float* Wih  = (const float*)d_in[1];   // [4096,1024]
  const float* Whh  = (const float*)d_in[2];   // [4096,1024]
  const float* bias = (const float*)d_in[3];   // [4096]
  float* out = (float*)d_out;

  char* ws = (char*)d_ws;
  // ws layout (bytes)
  const size_t o_xbf   = 0;                         // 33,554,432
  const size_t o_wih   = 33554432;                  //  8,388,608
  const size_t o_wpack = 41943040;                  //  8,388,608
  const size_t o_hbuf  = 50331648;                  //    262,144 (2 x 16384 u64)
  const size_t o_xw    = 50593792;                  // 256 MB (f32) or 128 MB (bf16)
  const bool xwf32 = ws_size >= (o_xw + (size_t)MM * GG * 4);

  short* xbf   = (short*)(ws + o_xbf);
  short* wihbf = (short*)(ws + o_wih);
  short* wpack = (short*)(ws + o_wpack);
  u64*   hbuf  = (u64*)(ws + o_hbuf);
  void*  xw    = (void*)(ws + o_xw);

  // zero h0 double-buffer (tags = 0 = step 0; ws is poisoned 0xAA each call)
  zero_ws<<<256, 256, 0, stream>>>((unsigned*)(ws + o_hbuf), 65536);
  // x -> bf16 (16,777,216 elems)
  cvt_bf16<<<16384, 256, 0, stream>>>(x, xbf, 4194304);
  // W_ih -> bf16 (4,194,304 elems)
  cvt_bf16<<<4096, 256, 0, stream>>>(Wih, wihbf, 1048576);
  // W_hh -> packed MFMA-B fragments
  pack_whh<<<2048, 256, 0, stream>>>(Whh, wpack);

  dim3 g1(GG / 128, MM / 128);  // (32, 128)
  if (xwf32) gemm_xw<true ><<<g1, 256, 0, stream>>>(xbf, wihbf, bias, xw);
  else       gemm_xw<false><<<g1, 256, 0, stream>>>(xbf, wihbf, bias, xw);

  if (xwf32) lstm_scan<true ><<<128, 256, 0, stream>>>(xw, wpack, hbuf, out);
  else       lstm_scan<false><<<128, 256, 0, stream>>>(xw, wpack, hbuf, out);
}

// Round 6
// 2588.947 us; speedup vs baseline: 2.3448x; 1.5017x over previous
//
#include <hip/hip_runtime.h>
#include <stdint.h>

// Problem constants: B=32, T=512, I=1024, H=1024, 4H=4096, M=B*T=16384.
#define BB 32
#define TT 512
#define KK 1024
#define GG 4096
#define MM 16384

#define INBOX_U64_PER_CWG 16384   // 128 KB per consumer WG (2 parities)
#define INBOX_PAR_U64 8192        // 64 KB per parity: 64 regions x 128 chunks

typedef __attribute__((ext_vector_type(8))) short short8;
typedef __attribute__((ext_vector_type(4))) short short4v;
typedef __attribute__((ext_vector_type(4))) float f32x4;
typedef unsigned long long u64;

__device__ inline short f2bf(float f) {
  union { float f; unsigned u; } v; v.f = f;
  unsigned r = (v.u + 0x7FFFu + ((v.u >> 16) & 1u)) >> 16;  // RNE
  return (short)(unsigned short)r;
}
__device__ inline float bf2f(short s) {
  union { unsigned u; float f; } v; v.u = ((unsigned)(unsigned short)s) << 16;
  return v.f;
}
__device__ inline float sigmoid_f(float x) { return 1.0f / (1.0f + __expf(-x)); }
__device__ inline float tanh_f(float x)    { return 1.0f - 2.0f / (__expf(2.0f * x) + 1.0f); }

// ---------------- prep kernels ----------------

__global__ void zero_ws(unsigned* __restrict__ p, int n) {
  int i = blockIdx.x * 256 + threadIdx.x;
  if (i < n) p[i] = 0u;
}

// float -> bf16, 4 elements/thread
__global__ void cvt_bf16(const float* __restrict__ in, short* __restrict__ out, int n4) {
  int i = blockIdx.x * 256 + threadIdx.x;
  if (i >= n4) return;
  f32x4 v = *(const f32x4*)(in + (size_t)i * 4);
  short4v o;
  o.x = f2bf(v.x); o.y = f2bf(v.y); o.z = f2bf(v.z); o.w = f2bf(v.w);
  *(short4v*)(out + (size_t)i * 4) = o;
}

// Pack W_hh into per-wave MFMA-B-fragment order for the scan.
// Col-group wgp (0..63) owns H-cols wgp*16..+15; wave wv4 (0..3) owns the
// 4 H-cols wgp*16 + wv4*4 + c, for all 4 gates, interleaved in the n-tile:
//   n = g*4 + c  ->  row(W_hh) = g*1024 + wgp*16 + wv4*4 + c
//   k(W_hh)      = s*32 + (lane>>4)*8 + j            (s = 0..31, full K)
// wpack[((wgp*4 + wv4)*32 + s)*512 + lane*8 + j]
__global__ void pack_whh(const float* __restrict__ Whh, short* __restrict__ wpack) {
  int idx = blockIdx.x * 256 + threadIdx.x;          // < 64*4*32*64 = 524288
  if (idx >= 524288) return;
  int lane = idx & 63;
  int s    = (idx >> 6) & 31;
  int wv4  = (idx >> 11) & 3;
  int wgp  = idx >> 13;
  int n = lane & 15, g = n >> 2, c = n & 3;
  int row  = g * 1024 + wgp * 16 + wv4 * 4 + c;
  int k    = s * 32 + (lane >> 4) * 8;
  const float* src = Whh + (size_t)row * KK + k;
  short8 v;
#pragma unroll
  for (int j = 0; j < 8; ++j) v[j] = f2bf(src[j]);
  *(short8*)(wpack + ((size_t)((wgp * 4 + wv4) * 32 + s)) * 512 + lane * 8) = v;
}

// ---------------- phase 1: xW = x @ W_ih^T + b ----------------
template <bool XWF32>
__global__ __launch_bounds__(256) void gemm_xw(const short* __restrict__ A,
                                               const short* __restrict__ Bw,
                                               const float* __restrict__ bias,
                                               void* __restrict__ Cv) {
  __shared__ short As[128 * 32];
  __shared__ short Bs[128 * 32];
  const int tid = threadIdx.x;
  const int m0 = blockIdx.y * 128;
  const int n0 = blockIdx.x * 128;
  const int lane = tid & 63, wv = tid >> 6;
  const int wm = (wv >> 1) * 64, wn = (wv & 1) * 64;
  const int fr = lane & 15;
  const int fq = (lane >> 4) * 8;
  const int quad = lane >> 4;
  f32x4 acc[4][4];
#pragma unroll
  for (int i = 0; i < 4; ++i)
#pragma unroll
    for (int j = 0; j < 4; ++j) acc[i][j] = (f32x4){0.f, 0.f, 0.f, 0.f};

  const int sr = tid >> 2;
  const int sc = (tid & 3) * 8;
  const short* Ag = A + (size_t)(m0 + sr) * KK + sc;
  const short* Bg = Bw + (size_t)(n0 + sr) * KK + sc;

  for (int kb = 0; kb < KK; kb += 32) {
    short8 a0 = *(const short8*)(Ag + kb);
    short8 a1 = *(const short8*)(Ag + (size_t)64 * KK + kb);
    short8 b0 = *(const short8*)(Bg + kb);
    short8 b1 = *(const short8*)(Bg + (size_t)64 * KK + kb);
    __syncthreads();
    *(short8*)&As[sr * 32 + sc] = a0;
    *(short8*)&As[(64 + sr) * 32 + sc] = a1;
    *(short8*)&Bs[sr * 32 + sc] = b0;
    *(short8*)&Bs[(64 + sr) * 32 + sc] = b1;
    __syncthreads();
    short8 af[4], bf[4];
#pragma unroll
    for (int i = 0; i < 4; ++i) {
      af[i] = *(const short8*)&As[(wm + i * 16 + fr) * 32 + fq];
      bf[i] = *(const short8*)&Bs[(wn + i * 16 + fr) * 32 + fq];
    }
#pragma unroll
    for (int i = 0; i < 4; ++i)
#pragma unroll
      for (int j = 0; j < 4; ++j)
        acc[i][j] = __builtin_amdgcn_mfma_f32_16x16x32_bf16(af[i], bf[j], acc[i][j], 0, 0, 0);
  }
#pragma unroll
  for (int i = 0; i < 4; ++i) {
    int mrow = m0 + wm + i * 16 + quad * 4;
#pragma unroll
    for (int j = 0; j < 4; ++j) {
      int ncol = n0 + wn + j * 16 + fr;
      float bv = bias[ncol];
#pragma unroll
      for (int r = 0; r < 4; ++r) {
        float v = acc[i][j][r] + bv;
        size_t idx = (size_t)(mrow + r) * GG + ncol;
        if (XWF32) ((float*)Cv)[idx] = v;
        else       ((short*)Cv)[idx] = f2bf(v);
      }
    }
  }
}

// ---------------- persistent LSTM scan (push-inbox exchange) ----------------
// 128 WGs x 256 thr: blockIdx = wgp*2 + half. half owns batch rows half*16..+15
// (independent 64-WG exchange groups). Wave wv4 owns 4 H-cols x 4 gates = one
// 16x16 n-tile (n=g*4+c), full K=1024 (32 MFMAs), W_hh B-frags in 128 VGPRs.
// Exchange is PUSH: each producer stores its tagged slice (128 u64 chunks
// [tag32 | 2 bf16]) into all 64 same-half consumers' PRIVATE inbox regions
// (relaxed sc1 stores, fire-and-forget, no drain/flag). A consumer validates
// only its own inbox, STREAMED in 4 batches of 8 chunks/thread (2 in flight:
// hv regs = 32 not 64 -> no spill; batch RTTs pipeline; a lagging producer
// stalls only its batch). Private regions kill r5's hot-line polling.
// Safety induction: producer pushes tag t+2 only after validating all tag-t+1
// chunks => every WG pushed t+1 => every WG staged step t => parity buffer
// (t&1) is fully consumed before overwrite. Stale early reads are rejected
// by the tag check; u64 atomic loads cannot tear payload from tag.
template <bool XWF32>
__global__ __launch_bounds__(256, 1) void lstm_scan(const void* __restrict__ xWv,
                                                    const short* __restrict__ wpack,
                                                    u64* __restrict__ inbox,
                                                    float* __restrict__ out) {
  const int wgp  = blockIdx.x >> 1;
  const int half = blockIdx.x & 1;
  const int tid  = threadIdx.x;
  const int lane = tid & 63;
  const int wv4  = tid >> 6;              // 0..3
  const int quad = lane >> 4;
  const int abrow = lane & 15;            // A-frag m index (local batch row)

  // preload W_hh B-fragments: 32 x short8 = 128 VGPRs per lane
  short8 wreg[32];
  {
    const short* wp = wpack + ((size_t)((wgp * 4 + wv4) * 32)) * 512 + lane * 8;
#pragma unroll
    for (int s = 0; s < 32; ++s) wreg[s] = *(const short8*)(wp + (size_t)s * 512);
  }

  __shared__ unsigned hstage[16 * 516];       // 16 h rows x 512 u32 (+4 pad), 33 KB
  __shared__ float partials[4 * 16 * 16];     // per-wave [n][b] z-tile, 4 KB
  __shared__ u64 slice[128];                  // this WG's outgoing tagged slice
  const short* hs = (const short*)hstage;

  const int gb = lane >> 2, gc = lane & 3;    // gate-thread: (local b, c)
  const int colg = wgp * 16 + wv4 * 4 + gc;   // global H-col
  const int browg = half * 16 + gb;           // global batch row
  float c_reg = 0.f;

  const float* xwf = (const float*)xWv;
  const short* xwh = (const short*)xWv;

  // this WG's own inbox (u64 units)
  const u64* mybox = inbox + (size_t)(wgp * 2 + half) * INBOX_U64_PER_CWG;

  // prefetch xW for t=0
  float xwv_[4];
#pragma unroll
  for (int g = 0; g < 4; ++g) {
    size_t xi = ((size_t)browg * TT) * GG + (size_t)g * 1024 + colg;
    xwv_[g] = XWF32 ? xwf[xi] : bf2f(xwh[xi]);
  }

  // validate one 8-chunk batch: retry stale (batched rounds), stage to LDS.
  // cid = q*128 + k (q = producer region, k = r*8 + cp)
  // hstage u32 index = r*516 + q*8 + cp
#define PROCESS_BATCH(HV, B)                                                    \
  {                                                                             \
    unsigned bad = 0;                                                           \
    _Pragma("unroll")                                                           \
    for (int i = 0; i < 8; ++i)                                                 \
      if ((unsigned)(HV[i] >> 32) != tg) bad |= (1u << i);                      \
    _Pragma("unroll 1")                                                         \
    while (bad) {                                                               \
      _Pragma("unroll")                                                         \
      for (int i = 0; i < 8; ++i)                                               \
        if (bad & (1u << i))                                                    \
          HV[i] = __hip_atomic_load(&src[(B) * 2048 + i * 256 + tid],           \
                                    __ATOMIC_RELAXED, __HIP_MEMORY_SCOPE_AGENT);\
      _Pragma("unroll")                                                         \
      for (int i = 0; i < 8; ++i)                                               \
        if ((unsigned)(HV[i] >> 32) == tg) bad &= ~(1u << i);                   \
    }                                                                           \
    _Pragma("unroll")                                                           \
    for (int i = 0; i < 8; ++i) {                                               \
      int cid = (B) * 2048 + i * 256 + tid;                                     \
      hstage[((cid >> 3) & 15) * 516 + (cid >> 7) * 8 + (cid & 7)] =            \
          (unsigned)HV[i];                                                      \
    }                                                                           \
  }

#pragma unroll 1
  for (int t = 0; t < TT; ++t) {
    const u64* src = mybox + (size_t)(t & 1) * INBOX_PAR_U64;
    const unsigned tg = (unsigned)t;

    // ---- streaming validate: 4 batches, 2 in flight ----
    u64 hv0[8], hv1[8];
#pragma unroll
    for (int i = 0; i < 8; ++i)
      hv0[i] = __hip_atomic_load(&src[i * 256 + tid], __ATOMIC_RELAXED,
                                 __HIP_MEMORY_SCOPE_AGENT);
#pragma unroll
    for (int i = 0; i < 8; ++i)
      hv1[i] = __hip_atomic_load(&src[2048 + i * 256 + tid], __ATOMIC_RELAXED,
                                 __HIP_MEMORY_SCOPE_AGENT);
    PROCESS_BATCH(hv0, 0);
#pragma unroll
    for (int i = 0; i < 8; ++i)
      hv0[i] = __hip_atomic_load(&src[2 * 2048 + i * 256 + tid], __ATOMIC_RELAXED,
                                 __HIP_MEMORY_SCOPE_AGENT);
    PROCESS_BATCH(hv1, 1);
#pragma unroll
    for (int i = 0; i < 8; ++i)
      hv1[i] = __hip_atomic_load(&src[3 * 2048 + i * 256 + tid], __ATOMIC_RELAXED,
                                 __HIP_MEMORY_SCOPE_AGENT);
    PROCESS_BATCH(hv0, 2);
    PROCESS_BATCH(hv1, 3);

    // S1: hstage ready (order LDS writes; no vmcnt drain)
    asm volatile("s_waitcnt lgkmcnt(0)" ::: "memory");
    __builtin_amdgcn_s_barrier();
    asm volatile("" ::: "memory");

    // prefetch xW(t+1); latency overlaps MFMA phase (consumed next step)
    float xwn[4];
    if (t + 1 < TT) {
#pragma unroll
      for (int g = 0; g < 4; ++g) {
        size_t xi = ((size_t)(browg * TT + t + 1)) * GG + (size_t)g * 1024 + colg;
        xwn[g] = XWF32 ? xwf[xi] : bf2f(xwh[xi]);
      }
    }

    // ---- MFMA: full K, A-frags from LDS, B-frags from registers ----
    f32x4 acc = (f32x4){0.f, 0.f, 0.f, 0.f};
#pragma unroll
    for (int s = 0; s < 32; ++s) {
      short8 a = *(const short8*)&hs[abrow * 1032 + s * 32 + quad * 8];
      acc = __builtin_amdgcn_mfma_f32_16x16x32_bf16(a, wreg[s], acc, 0, 0, 0);
    }
    // C/D: col = lane&15 = n = g*4+c, row = quad*4+reg = local b -> [n][b]
    *(f32x4*)&partials[wv4 * 256 + (lane & 15) * 16 + quad * 4] = acc;

    // S2: partials ready
    asm volatile("s_waitcnt lgkmcnt(0)" ::: "memory");
    __builtin_amdgcn_s_barrier();
    asm volatile("" ::: "memory");

    // ---- gates ----
    float z[4];
#pragma unroll
    for (int g = 0; g < 4; ++g)
      z[g] = partials[wv4 * 256 + (g * 4 + gc) * 16 + gb] + xwv_[g];

    float i_ = sigmoid_f(z[0]);
    float f_ = sigmoid_f(z[1]);
    float g_ = tanh_f(z[2]);
    float o_ = sigmoid_f(z[3]);
    c_reg = f_ * c_reg + i_ * g_;
    float h_ = o_ * tanh_f(c_reg);
    out[((size_t)browg * TT + t) * 1024 + colg] = h_;  // plain store, never drained

    if (t + 1 < TT) {
      // build outgoing tagged slice in LDS (even-gc lanes own a col-pair)
      unsigned hb16 = (unsigned)(unsigned short)f2bf(h_);
      unsigned oth = __shfl_xor(hb16, 1, 64);
      if (!(gc & 1)) {
        int k = gb * 8 + wv4 * 2 + (gc >> 1);
        slice[k] = ((u64)(unsigned)(t + 1) << 32) | (u64)(hb16 | (oth << 16));
      }
      // S3: slice ready
      asm volatile("s_waitcnt lgkmcnt(0)" ::: "memory");
      __builtin_amdgcn_s_barrier();
      asm volatile("" ::: "memory");

      // ---- push: 32 coalesced sc1 stores/thread to 64 private inboxes ----
      u64 sv0 = slice[lane];
      u64 sv1 = slice[64 + lane];
      size_t poff = (size_t)((t + 1) & 1) * INBOX_PAR_U64 + (size_t)wgp * 128;
#pragma unroll
      for (int j = 0; j < 16; ++j) {
        int cons = j * 4 + wv4;
        u64* dst = inbox + (size_t)(cons * 2 + half) * INBOX_U64_PER_CWG + poff;
        __hip_atomic_store(&dst[lane], sv0, __ATOMIC_RELAXED,
                           __HIP_MEMORY_SCOPE_AGENT);
        __hip_atomic_store(&dst[64 + lane], sv1, __ATOMIC_RELAXED,
                           __HIP_MEMORY_SCOPE_AGENT);
      }
#pragma unroll
      for (int g = 0; g < 4; ++g) xwv_[g] = xwn[g];
    }
  }
#undef PROCESS_BATCH
}

// ---------------- launch ----------------

extern "C" void kernel_launch(void* const* d_in, const int* in_sizes, int n_in,
                              void* d_out, int out_size, void* d_ws, size_t ws_size,
                              hipStream_t stream) {
  const float* x    = (const float*)d_in[0];   // [32,512,1024]
  const float* Wih  = (const float*)d_in[1];   // [4096,1024]
  const float* Whh  = (const float*)d_in[2];   // [4096,1024]
  const float* bias = (const float*)d_in[3];   // [4096]
  float* out = (float*)d_out;

  char* ws = (char*)d_ws;
  // ws layout (bytes). The 16 MB inbox REUSES the xbf region (gemm has
  // consumed xbf before zero_ws+scan run; stream order guarantees safety).
  const size_t o_xbf   = 0;                         // 33,554,432 (xbf, then inbox)
  const size_t o_wih   = 33554432;                  //  8,388,608
  const size_t o_wpack = 41943040;                  //  8,388,608
  const size_t o_xw    = 50331648;                  // 256 MB (f32) or 128 MB (bf16)
  const bool xwf32 = ws_size >= (o_xw + (size_t)MM * GG * 4);

  short* xbf   = (short*)(ws + o_xbf);
  short* wihbf = (short*)(ws + o_wih);
  short* wpack = (short*)(ws + o_wpack);
  u64*   inbox = (u64*)(ws + o_xbf);               // 16,777,216 bytes
  void*  xw    = (void*)(ws + o_xw);

  // x -> bf16 (16,777,216 elems)
  cvt_bf16<<<16384, 256, 0, stream>>>(x, xbf, 4194304);
  // W_ih -> bf16 (4,194,304 elems)
  cvt_bf16<<<4096, 256, 0, stream>>>(Wih, wihbf, 1048576);
  // W_hh -> packed MFMA-B fragments
  pack_whh<<<2048, 256, 0, stream>>>(Whh, wpack);

  dim3 g1(GG / 128, MM / 128);  // (32, 128)
  if (xwf32) gemm_xw<true ><<<g1, 256, 0, stream>>>(xbf, wihbf, bias, xw);
  else       gemm_xw<false><<<g1, 256, 0, stream>>>(xbf, wihbf, bias, xw);

  // zero the inbox AFTER gemm consumed xbf: tags=0 & h0=0 for t=0
  zero_ws<<<16384, 256, 0, stream>>>((unsigned*)(ws + o_xbf), 4194304);

  if (xwf32) lstm_scan<true ><<<128, 256, 0, stream>>>(xw, wpack, inbox, out);
  else       lstm_scan<false><<<128, 256, 0, stream>>>(xw, wpack, inbox, out);
}